// Round 1
// baseline (28453.558 us; speedup 1.0000x reference)
//
#include <hip/hip_runtime.h>
#include <math.h>

#define BN_EPS 1e-5f

// ---------------------------------------------------------------------------
// Workspace layout (float offsets):
//  We    @ 0         (64*84)        encoder weight, BN folded
//  be    @ 8192      (64)
//  W2    @ 12288     (1024*64)      lin_w with repeat-16 folded: [o2][c]
//  A     @ 81920     (256*64*16)    x-path -> gates i,f matrix: [go][c][p]
//  Abias @ 344064    (256*16)       bias for gates i,f (incl cell_b)
//  enc   @ 352256    (262144*64)    relu encoder output [b*128+t][c]
//  G     @ 17129472  (2048*512*16)  gate preactivations [b][go][p]
//  h     @ 33906688  (2048*128*16)
//  c     @ 38100992  (2048*128*16)
//  total 42295296 floats = ~169 MB
// ---------------------------------------------------------------------------

__global__ void prep_enc_w(const float* __restrict__ conv1d_w,
                           const float* __restrict__ conv1d_b,
                           const float* __restrict__ gamma,
                           const float* __restrict__ beta,
                           const float* __restrict__ mean,
                           const float* __restrict__ var,
                           float* __restrict__ We, float* __restrict__ be) {
  int tid = blockIdx.x * blockDim.x + threadIdx.x;
  if (tid < 5376) {
    int c = tid / 84, f = tid % 84;
    float s = gamma[c] * rsqrtf(var[c] + BN_EPS);
    We[c * 84 + f] = s * conv1d_w[c * 252 + f * 3 + 1];  // center tap only
    if (f == 0) be[c] = s * conv1d_b[c] + (beta[c] - mean[c] * s);
  }
}

__global__ void prep_w2(const float* __restrict__ lin_w, float* __restrict__ W2) {
  int tid = blockIdx.x * blockDim.x + threadIdx.x;  // 65536
  int o2 = tid >> 6, c = tid & 63;
  float s = 0.f;
#pragma unroll
  for (int j = 0; j < 16; ++j) s += lin_w[o2 * 1024 + c * 16 + j];
  W2[o2 * 64 + c] = s;  // [o2][c]
}

// Build A[(go,p)][c]: composition of (lin -> reshape 64x4x4 -> conv3x3 taps)
// for the x-dependent inputs of gates i (go<128, x-ch 0..47) and f
// (go in 128..255, x-ch 48..63 == group-1 k=0..15).
__global__ void prep_A(const float* __restrict__ cell_w,
                       const float* __restrict__ cell_b,
                       const float* __restrict__ lin_b,
                       const float* __restrict__ W2,
                       float* __restrict__ A, float* __restrict__ Abias) {
  int tid = blockIdx.x * blockDim.x + threadIdx.x;  // 262144
  int go = tid >> 10;
  int c = (tid >> 4) & 63;
  int p = tid & 15;
  int y = p >> 2, x = p & 3;
  int kn = (go >= 128) ? 16 : 48;
  int xb = (go >= 128) ? 48 : 0;
  float a = 0.f;
  for (int k = 0; k < kn; ++k)
    for (int dy = 0; dy < 3; ++dy) {
      int yy = y + dy - 1;
      if (yy < 0 || yy > 3) continue;
      for (int dx = 0; dx < 3; ++dx) {
        int xx = x + dx - 1;
        if (xx < 0 || xx > 3) continue;
        a += cell_w[((go * 48 + k) * 3 + dy) * 3 + dx] *
             W2[((xb + k) * 16 + yy * 4 + xx) * 64 + c];
      }
    }
  A[(go * 64 + c) * 16 + p] = a;  // [go][c][p]
  if (c == 0) {
    float bs = cell_b[go];
    for (int k = 0; k < kn; ++k)
      for (int dy = 0; dy < 3; ++dy) {
        int yy = y + dy - 1;
        if (yy < 0 || yy > 3) continue;
        for (int dx = 0; dx < 3; ++dx) {
          int xx = x + dx - 1;
          if (xx < 0 || xx > 3) continue;
          bs += cell_w[((go * 48 + k) * 3 + dy) * 3 + dx] *
                lin_b[(xb + k) * 16 + yy * 4 + xx];
        }
      }
    Abias[go * 16 + p] = bs;
  }
}

// enc[r][c] = relu(x[r] . We[c] + be[c]), r = b*128+t
__global__ __launch_bounds__(256) void encoder_kernel(
    const float* __restrict__ x, const float* __restrict__ We,
    const float* __restrict__ be, float* __restrict__ enc) {
  int r = blockIdx.x * 256 + threadIdx.x;  // 262144 rows
  float4 xr[21];
  const float4* xp = (const float4*)(x + (size_t)r * 84);
#pragma unroll
  for (int i = 0; i < 21; ++i) xr[i] = xp[i];
  float4* ep = (float4*)(enc + (size_t)r * 64);
  for (int c4 = 0; c4 < 16; ++c4) {
    float o4[4];
#pragma unroll
    for (int cc = 0; cc < 4; ++cc) {
      int c = c4 * 4 + cc;
      float a = be[c];  // wave-uniform -> scalar loads
      const float* wc = We + c * 84;
#pragma unroll
      for (int i = 0; i < 21; ++i) {
        a += xr[i].x * wc[i * 4 + 0] + xr[i].y * wc[i * 4 + 1] +
             xr[i].z * wc[i * 4 + 2] + xr[i].w * wc[i * 4 + 3];
      }
      o4[cc] = fmaxf(a, 0.f);
    }
    ep[c4] = make_float4(o4[0], o4[1], o4[2], o4[3]);
  }
}

// Per step: one thread per gate output channel go in [0,512); NB batches/block.
// go<256: A-part (K=64 from enc). go>=128: conv over h channels in LDS.
#define NB 4
__global__ __launch_bounds__(512) void gate_kernel(
    const float* __restrict__ enc, const float* __restrict__ h,
    const float* __restrict__ A, const float* __restrict__ Abias,
    const float* __restrict__ cell_w, const float* __restrict__ cell_b,
    float* __restrict__ G, int t) {
  __shared__ __align__(16) float h_s[NB * 2048];   // [b][ch][p] 32 KB
  __shared__ __align__(16) float enc_s[NB * 64];
  int go = threadIdx.x;
  int b0 = blockIdx.x * NB;
  {
    const float4* src = (const float4*)(h + (size_t)b0 * 2048);
    float4* dst = (float4*)h_s;
    for (int i = go; i < NB * 512; i += 512) dst[i] = src[i];
    for (int i = go; i < NB * 64; i += 512) {
      int bb = i >> 6, cc = i & 63;
      enc_s[i] = enc[((size_t)(b0 + bb) * 128 + t) * 64 + cc];
    }
  }
  __syncthreads();

  float acc[NB][16];
  if (go < 256) {
#pragma unroll
    for (int p = 0; p < 16; ++p) {
      float ab = Abias[go * 16 + p];
#pragma unroll
      for (int b = 0; b < NB; ++b) acc[b][p] = ab;
    }
    const float4* Ago = (const float4*)(A + (size_t)go * 1024);
#pragma unroll 2
    for (int c = 0; c < 64; ++c) {
      float4 a0 = Ago[c * 4 + 0];
      float4 a1 = Ago[c * 4 + 1];
      float4 a2 = Ago[c * 4 + 2];
      float4 a3 = Ago[c * 4 + 3];
#pragma unroll
      for (int b = 0; b < NB; ++b) {
        float e = enc_s[b * 64 + c];
        acc[b][0] += e * a0.x;  acc[b][1] += e * a0.y;
        acc[b][2] += e * a0.z;  acc[b][3] += e * a0.w;
        acc[b][4] += e * a1.x;  acc[b][5] += e * a1.y;
        acc[b][6] += e * a1.z;  acc[b][7] += e * a1.w;
        acc[b][8] += e * a2.x;  acc[b][9] += e * a2.y;
        acc[b][10] += e * a2.z; acc[b][11] += e * a2.w;
        acc[b][12] += e * a3.x; acc[b][13] += e * a3.y;
        acc[b][14] += e * a3.z; acc[b][15] += e * a3.w;
      }
    }
  } else {
    float cb = cell_b[go];
#pragma unroll
    for (int b = 0; b < NB; ++b)
#pragma unroll
      for (int p = 0; p < 16; ++p) acc[b][p] = cb;
  }

  if (go >= 128) {
    int gate = go >> 7;                                   // 1=f 2=o 3=g
    int hbase = (gate == 1) ? 0 : ((gate == 2) ? 32 : 80);
    int nci = (gate == 1) ? 32 : 48;
    int kofs = (gate == 1) ? 16 : 0;
    for (int ci = 0; ci < nci; ++ci) {
      const float* wp = cell_w + ((size_t)go * 48 + kofs + ci) * 9;
      float w[9];
#pragma unroll
      for (int j = 0; j < 9; ++j) w[j] = wp[j];
      const float* hb = h_s + (hbase + ci) * 16;
#pragma unroll
      for (int b = 0; b < NB; ++b) {
        const float4* hr4 = (const float4*)(hb + b * 2048);
        float4 h0 = hr4[0], h1 = hr4[1], h2 = hr4[2], h3 = hr4[3];
        float hr[16] = {h0.x, h0.y, h0.z, h0.w, h1.x, h1.y, h1.z, h1.w,
                        h2.x, h2.y, h2.z, h2.w, h3.x, h3.y, h3.z, h3.w};
#pragma unroll
        for (int dy = 0; dy < 3; ++dy)
#pragma unroll
          for (int dx = 0; dx < 3; ++dx) {
            float ww = w[dy * 3 + dx];
#pragma unroll
            for (int yy = (dy == 0 ? 1 : 0); yy <= (dy == 2 ? 2 : 3); ++yy)
#pragma unroll
              for (int xx = (dx == 0 ? 1 : 0); xx <= (dx == 2 ? 2 : 3); ++xx)
                acc[b][yy * 4 + xx] += ww * hr[(yy + dy - 1) * 4 + (xx + dx - 1)];
          }
      }
    }
  }

#pragma unroll
  for (int b = 0; b < NB; ++b) {
    float4* Gp = (float4*)(G + (((size_t)(b0 + b)) * 512 + go) * 16);
    Gp[0] = make_float4(acc[b][0], acc[b][1], acc[b][2], acc[b][3]);
    Gp[1] = make_float4(acc[b][4], acc[b][5], acc[b][6], acc[b][7]);
    Gp[2] = make_float4(acc[b][8], acc[b][9], acc[b][10], acc[b][11]);
    Gp[3] = make_float4(acc[b][12], acc[b][13], acc[b][14], acc[b][15]);
  }
}

__device__ __forceinline__ float sigm(float v) {
  return __fdividef(1.f, 1.f + __expf(-v));
}
__device__ __forceinline__ float tanh_fast(float v) {
  return 1.f - __fdividef(2.f, __expf(2.f * v) + 1.f);
}

__global__ __launch_bounds__(256) void cell_kernel(
    const float* __restrict__ G, float* __restrict__ c, float* __restrict__ h) {
  int idx = blockIdx.x * 256 + threadIdx.x;  // 2048*128*16
  int b = idx >> 11;
  int cp = idx & 2047;
  const float* Gb = G + (size_t)b * 8192;
  float iv = Gb[cp];
  float fv = Gb[2048 + cp];
  float ov = Gb[4096 + cp];
  float gv = Gb[6144 + cp];
  float cn = sigm(fv) * c[idx] + sigm(iv) * tanh_fast(gv);
  c[idx] = cn;
  h[idx] = sigm(ov) * tanh_fast(cn);
}

__global__ __launch_bounds__(128) void cls_kernel(
    const float* __restrict__ h, const float* __restrict__ w1,
    const float* __restrict__ b1, const float* __restrict__ w2,
    const float* __restrict__ b2, float* __restrict__ out) {
  __shared__ __align__(16) float feat[8 * 2048];  // 64 KB
  __shared__ float hid[8 * 128];
  int b0 = blockIdx.x * 8;
  {
    const float4* src = (const float4*)(h + (size_t)b0 * 2048);
    float4* dst = (float4*)feat;
    for (int i = threadIdx.x; i < 4096; i += 128) dst[i] = src[i];
  }
  __syncthreads();
  int ch = threadIdx.x;
  float acc[8];
#pragma unroll
  for (int b = 0; b < 8; ++b) acc[b] = b1[ch];
  const float4* wr = (const float4*)(w1 + (size_t)ch * 2048);
  for (int k4 = 0; k4 < 512; ++k4) {
    float4 w = wr[k4];
#pragma unroll
    for (int b = 0; b < 8; ++b) {
      float4 f = ((const float4*)(feat + b * 2048))[k4];
      acc[b] += w.x * f.x + w.y * f.y + w.z * f.z + w.w * f.w;
    }
  }
#pragma unroll
  for (int b = 0; b < 8; ++b) hid[b * 128 + ch] = fmaxf(acc[b], 0.f);
  __syncthreads();
  if (threadIdx.x < 16) {
    int b = threadIdx.x >> 1, o = threadIdx.x & 1;
    float s = b2[o];
    for (int k = 0; k < 128; ++k) s += hid[b * 128 + k] * w2[o * 128 + k];
    out[(size_t)(b0 + b) * 2 + o] = s;
  }
}

extern "C" void kernel_launch(void* const* d_in, const int* in_sizes, int n_in,
                              void* d_out, int out_size, void* d_ws, size_t ws_size,
                              hipStream_t stream) {
  const float* x        = (const float*)d_in[0];
  const float* conv1d_w = (const float*)d_in[1];
  const float* conv1d_b = (const float*)d_in[2];
  const float* bn_gamma = (const float*)d_in[3];
  const float* bn_beta  = (const float*)d_in[4];
  const float* bn_mean  = (const float*)d_in[5];
  const float* bn_var   = (const float*)d_in[6];
  const float* lin_w    = (const float*)d_in[7];
  const float* lin_b    = (const float*)d_in[8];
  const float* cell_w   = (const float*)d_in[9];
  const float* cell_b   = (const float*)d_in[10];
  const float* cls1_w   = (const float*)d_in[11];
  const float* cls1_b   = (const float*)d_in[12];
  const float* cls2_w   = (const float*)d_in[13];
  const float* cls2_b   = (const float*)d_in[14];

  float* ws    = (float*)d_ws;
  float* We    = ws + 0;
  float* be    = ws + 8192;
  float* W2    = ws + 12288;
  float* A     = ws + 81920;
  float* Abias = ws + 344064;
  float* enc   = ws + 352256;
  float* G     = ws + 17129472;
  float* hbuf  = ws + 33906688;
  float* cbuf  = ws + 38100992;
  float* out   = (float*)d_out;

  prep_enc_w<<<21, 256, 0, stream>>>(conv1d_w, conv1d_b, bn_gamma, bn_beta,
                                     bn_mean, bn_var, We, be);
  prep_w2<<<256, 256, 0, stream>>>(lin_w, W2);
  prep_A<<<1024, 256, 0, stream>>>(cell_w, cell_b, lin_b, W2, A, Abias);
  encoder_kernel<<<1024, 256, 0, stream>>>(x, We, be, enc);
  hipMemsetAsync(hbuf, 0, 4194304 * sizeof(float), stream);
  hipMemsetAsync(cbuf, 0, 4194304 * sizeof(float), stream);
  for (int t = 0; t < 128; ++t) {
    gate_kernel<<<512, 512, 0, stream>>>(enc, hbuf, A, Abias, cell_w, cell_b, G, t);
    cell_kernel<<<16384, 256, 0, stream>>>(G, cbuf, hbuf);
  }
  cls_kernel<<<256, 128, 0, stream>>>(hbuf, cls1_w, cls1_b, cls2_w, cls2_b, out);
}

// Round 2
// 23517.690 us; speedup vs baseline: 1.2099x; 1.2099x over previous
//
#include <hip/hip_runtime.h>
#include <math.h>

#define BN_EPS 1e-5f

typedef _Float16 half8_t __attribute__((ext_vector_type(8)));

// ---------------------------------------------------------------------------
// Workspace layout (float offsets):
//  We    @ 0         (5376)   encoder weight, BN folded
//  be    @ 8192      (64)
//  W2    @ 12288     (65536)  lin_w repeat-16 folded [o2][c]
//  A     @ 81920     (262144) x-path gates i,f: [go][c][p] fp32
//  Abias @ 344064    (4096)
//  enc   @ 352256    (16777216) relu encoder out [b*128+t][c]
//  Apk   @ 17129472  (262144 halves = 131072 floats) [c][go][p] f16
//  Wpk   @ 17260544  (262144 halves) [f|o|g][(ci*128+ch)*16] f16
//  hbuf  @ 17391616  (4194304) final h
// ---------------------------------------------------------------------------

__global__ void prep_enc_w(const float* __restrict__ conv1d_w,
                           const float* __restrict__ conv1d_b,
                           const float* __restrict__ gamma,
                           const float* __restrict__ beta,
                           const float* __restrict__ mean,
                           const float* __restrict__ var,
                           float* __restrict__ We, float* __restrict__ be) {
  int tid = blockIdx.x * blockDim.x + threadIdx.x;
  if (tid < 5376) {
    int c = tid / 84, f = tid % 84;
    float s = gamma[c] * rsqrtf(var[c] + BN_EPS);
    We[c * 84 + f] = s * conv1d_w[c * 252 + f * 3 + 1];
    if (f == 0) be[c] = s * conv1d_b[c] + (beta[c] - mean[c] * s);
  }
}

__global__ void prep_w2(const float* __restrict__ lin_w, float* __restrict__ W2) {
  int tid = blockIdx.x * blockDim.x + threadIdx.x;  // 65536
  int o2 = tid >> 6, c = tid & 63;
  float s = 0.f;
#pragma unroll
  for (int j = 0; j < 16; ++j) s += lin_w[o2 * 1024 + c * 16 + j];
  W2[o2 * 64 + c] = s;
}

__global__ void prep_A(const float* __restrict__ cell_w,
                       const float* __restrict__ cell_b,
                       const float* __restrict__ lin_b,
                       const float* __restrict__ W2,
                       float* __restrict__ A, float* __restrict__ Abias) {
  int tid = blockIdx.x * blockDim.x + threadIdx.x;  // 262144
  int go = tid >> 10;
  int c = (tid >> 4) & 63;
  int p = tid & 15;
  int y = p >> 2, x = p & 3;
  int kn = (go >= 128) ? 16 : 48;
  int xb = (go >= 128) ? 48 : 0;
  float a = 0.f;
  for (int k = 0; k < kn; ++k)
    for (int dy = 0; dy < 3; ++dy) {
      int yy = y + dy - 1;
      if (yy < 0 || yy > 3) continue;
      for (int dx = 0; dx < 3; ++dx) {
        int xx = x + dx - 1;
        if (xx < 0 || xx > 3) continue;
        a += cell_w[((go * 48 + k) * 3 + dy) * 3 + dx] *
             W2[((xb + k) * 16 + yy * 4 + xx) * 64 + c];
      }
    }
  A[(go * 64 + c) * 16 + p] = a;
  if (c == 0) {
    float bs = cell_b[go];
    for (int k = 0; k < kn; ++k)
      for (int dy = 0; dy < 3; ++dy) {
        int yy = y + dy - 1;
        if (yy < 0 || yy > 3) continue;
        for (int dx = 0; dx < 3; ++dx) {
          int xx = x + dx - 1;
          if (xx < 0 || xx > 3) continue;
          bs += cell_w[((go * 48 + k) * 3 + dy) * 3 + dx] *
                lin_b[(xb + k) * 16 + yy * 4 + xx];
        }
      }
    Abias[go * 16 + p] = bs;
  }
}

// A [go][c][p] fp32 -> Apk [c][go][p] f16  (go contiguous for coalescing)
__global__ void pack_apk(const float* __restrict__ A, _Float16* __restrict__ Apk) {
  int tid = blockIdx.x * blockDim.x + threadIdx.x;  // 262144
  int go = tid >> 10, c = (tid >> 4) & 63, p = tid & 15;
  Apk[((size_t)c * 256 + go) * 16 + p] = (_Float16)A[tid];
}

// cell_w -> Wpk f16: [f rows 0..31 | o rows 0..47 | g rows 0..47], row=(ci*128+ch)*16
__global__ void pack_wpk(const float* __restrict__ cell_w, _Float16* __restrict__ Wpk) {
  int tid = blockIdx.x * blockDim.x + threadIdx.x;  // 262144
  int row = tid >> 4, j = tid & 15;
  int cirow = row >> 7, ch = row & 127;
  int go, ci, kofs;
  if (cirow < 32)      { go = 128 + ch; ci = cirow;      kofs = 16; }
  else if (cirow < 80) { go = 256 + ch; ci = cirow - 32; kofs = 0; }
  else                 { go = 384 + ch; ci = cirow - 80; kofs = 0; }
  float v = (j < 9) ? cell_w[((size_t)go * 48 + kofs + ci) * 9 + j] : 0.f;
  Wpk[tid] = (_Float16)v;
}

__global__ __launch_bounds__(256) void encoder_kernel(
    const float* __restrict__ x, const float* __restrict__ We,
    const float* __restrict__ be, float* __restrict__ enc) {
  int r = blockIdx.x * 256 + threadIdx.x;  // 262144 rows
  float4 xr[21];
  const float4* xp = (const float4*)(x + (size_t)r * 84);
#pragma unroll
  for (int i = 0; i < 21; ++i) xr[i] = xp[i];
  float4* ep = (float4*)(enc + (size_t)r * 64);
  for (int c4 = 0; c4 < 16; ++c4) {
    float o4[4];
#pragma unroll
    for (int cc = 0; cc < 4; ++cc) {
      int c = c4 * 4 + cc;
      float a = be[c];
      const float* wc = We + c * 84;
#pragma unroll
      for (int i = 0; i < 21; ++i) {
        a += xr[i].x * wc[i * 4 + 0] + xr[i].y * wc[i * 4 + 1] +
             xr[i].z * wc[i * 4 + 2] + xr[i].w * wc[i * 4 + 3];
      }
      o4[cc] = fmaxf(a, 0.f);
    }
    ep[c4] = make_float4(o4[0], o4[1], o4[2], o4[3]);
  }
}

__device__ __forceinline__ float sigm(float v) {
  return __fdividef(1.f, 1.f + __expf(-v));
}
__device__ __forceinline__ float tanh_fast(float v) {
  return 1.f - __fdividef(2.f, __expf(2.f * v) + 1.f);
}

#define HB_STRIDE 2564   // per-batch float stride in h_s (pad 4 -> bank spread)
#define HC_STRIDE 20     // per-channel float stride (pad 4, keeps 16B align)

__device__ __forceinline__ void apart_accum(float acc[16],
                                            const _Float16* __restrict__ Apk,
                                            const float4* __restrict__ esv, int go) {
  const half8_t* ap = (const half8_t*)Apk + (size_t)go * 2;
#pragma unroll 2
  for (int c4 = 0; c4 < 16; ++c4) {
    float4 e4 = esv[c4];
    float ev[4] = {e4.x, e4.y, e4.z, e4.w};
#pragma unroll
    for (int k = 0; k < 4; ++k) {
      float e = ev[k];
      half8_t lo = ap[(size_t)(c4 * 4 + k) * 512];
      half8_t hi = ap[(size_t)(c4 * 4 + k) * 512 + 1];
#pragma unroll
      for (int p = 0; p < 8; ++p) acc[p] += e * (float)lo[p];
#pragma unroll
      for (int p = 0; p < 8; ++p) acc[8 + p] += e * (float)hi[p];
    }
  }
}

__device__ __forceinline__ void conv_accum(float acc[16],
                                           const _Float16* __restrict__ W,
                                           const float* __restrict__ hb,
                                           int hbase, int nci, int ch) {
#pragma unroll 2
  for (int ci = 0; ci < nci; ++ci) {
    const _Float16* wr = W + ((size_t)(ci * 128 + ch) << 4);
    half8_t w8 = *(const half8_t*)wr;
    float w[9];
#pragma unroll
    for (int j = 0; j < 8; ++j) w[j] = (float)w8[j];
    w[8] = (float)wr[8];
    const float4* hr4 = (const float4*)(hb + (hbase + ci) * HC_STRIDE);
    float4 h0 = hr4[0], h1 = hr4[1], h2 = hr4[2], h3 = hr4[3];
    float hr[16] = {h0.x, h0.y, h0.z, h0.w, h1.x, h1.y, h1.z, h1.w,
                    h2.x, h2.y, h2.z, h2.w, h3.x, h3.y, h3.z, h3.w};
#pragma unroll
    for (int dy = 0; dy < 3; ++dy)
#pragma unroll
      for (int dx = 0; dx < 3; ++dx) {
        float ww = w[dy * 3 + dx];
#pragma unroll
        for (int yy = (dy == 0 ? 1 : 0); yy <= (dy == 2 ? 2 : 3); ++yy)
#pragma unroll
          for (int xx = (dx == 0 ? 1 : 0); xx <= (dx == 2 ? 2 : 3); ++xx)
            acc[yy * 4 + xx] += ww * hr[(yy + dy - 1) * 4 + (xx + dx - 1)];
      }
  }
}

// Persistent recurrence: 256 blocks x 1024 threads, block owns 8 batches x 128 steps.
// Thread (b,ch) owns all 4 gates + cell for its (b,ch,16p); c in VGPRs, h in LDS.
__global__ __launch_bounds__(1024) void recur_kernel(
    const float* __restrict__ enc, const _Float16* __restrict__ Apk,
    const float* __restrict__ Abias, const _Float16* __restrict__ Wpk,
    const float* __restrict__ cell_b, float* __restrict__ hout) {
  __shared__ float h_s[8 * HB_STRIDE];
  __shared__ float enc_s[2][8][68];
  const int tid = threadIdx.x;
  // lane map: wave = 8 ch x 8 b (batch-duplicated lanes -> coalesced weight loads)
  const int ch = ((tid >> 6) << 3) | (tid & 7);
  const int b = (tid >> 3) & 7;
  const int b0 = blockIdx.x * 8;

  for (int i = tid; i < 8 * HB_STRIDE; i += 1024) h_s[i] = 0.f;

  float c_r[16];
#pragma unroll
  for (int p = 0; p < 16; ++p) c_r[p] = 0.f;
  const float cb_o = cell_b[256 + ch];
  const float cb_g = cell_b[384 + ch];

  const _Float16* Wf = Wpk;
  const _Float16* Wo = Wpk + 65536;
  const _Float16* Wg = Wpk + 163840;
  const float* hb = h_s + b * HB_STRIDE;

  if (tid < 512) {
    int bb = tid >> 6, cc = tid & 63;
    enc_s[0][bb][cc] = enc[((size_t)(b0 + bb) * 128 + 0) * 64 + cc];
  }
  __syncthreads();

  for (int t = 0; t < 128; ++t) {
    const float4* esv = (const float4*)(&enc_s[t & 1][b][0]);
    float acc[16], tg[16];

    // ---- gate f: A-part(go=128+ch) + conv(h 0..31) ----
    {
      const float4* ab = (const float4*)(Abias + ((128 + ch) << 4));
      float4 a0 = ab[0], a1 = ab[1], a2 = ab[2], a3 = ab[3];
      acc[0]=a0.x; acc[1]=a0.y; acc[2]=a0.z; acc[3]=a0.w;
      acc[4]=a1.x; acc[5]=a1.y; acc[6]=a1.z; acc[7]=a1.w;
      acc[8]=a2.x; acc[9]=a2.y; acc[10]=a2.z; acc[11]=a2.w;
      acc[12]=a3.x; acc[13]=a3.y; acc[14]=a3.z; acc[15]=a3.w;
      apart_accum(acc, Apk, esv, 128 + ch);
      conv_accum(acc, Wf, hb, 0, 32, ch);
#pragma unroll
      for (int p = 0; p < 16; ++p) c_r[p] *= sigm(acc[p]);
    }
    // ---- gate g: conv(h 80..127) ----
    {
#pragma unroll
      for (int p = 0; p < 16; ++p) acc[p] = cb_g;
      conv_accum(acc, Wg, hb, 80, 48, ch);
#pragma unroll
      for (int p = 0; p < 16; ++p) tg[p] = tanh_fast(acc[p]);
    }
    // ---- gate i: A-part(go=ch) ----
    {
      const float4* ab = (const float4*)(Abias + (ch << 4));
      float4 a0 = ab[0], a1 = ab[1], a2 = ab[2], a3 = ab[3];
      acc[0]=a0.x; acc[1]=a0.y; acc[2]=a0.z; acc[3]=a0.w;
      acc[4]=a1.x; acc[5]=a1.y; acc[6]=a1.z; acc[7]=a1.w;
      acc[8]=a2.x; acc[9]=a2.y; acc[10]=a2.z; acc[11]=a2.w;
      acc[12]=a3.x; acc[13]=a3.y; acc[14]=a3.z; acc[15]=a3.w;
      apart_accum(acc, Apk, esv, ch);
#pragma unroll
      for (int p = 0; p < 16; ++p) c_r[p] += sigm(acc[p]) * tg[p];
    }
    // ---- gate o: conv(h 32..79) ----
    float hn[16];
    {
#pragma unroll
      for (int p = 0; p < 16; ++p) acc[p] = cb_o;
      conv_accum(acc, Wo, hb, 32, 48, ch);
#pragma unroll
      for (int p = 0; p < 16; ++p) hn[p] = sigm(acc[p]) * tanh_fast(c_r[p]);
    }

    __syncthreads();  // all reads of h_s(t) done
    {
      float4* hw = (float4*)(h_s + b * HB_STRIDE + ch * HC_STRIDE);
      hw[0] = make_float4(hn[0], hn[1], hn[2], hn[3]);
      hw[1] = make_float4(hn[4], hn[5], hn[6], hn[7]);
      hw[2] = make_float4(hn[8], hn[9], hn[10], hn[11]);
      hw[3] = make_float4(hn[12], hn[13], hn[14], hn[15]);
    }
    if (tid < 512 && t + 1 < 128) {
      int bb = tid >> 6, cc = tid & 63;
      enc_s[(t + 1) & 1][bb][cc] = enc[((size_t)(b0 + bb) * 128 + (t + 1)) * 64 + cc];
    }
    __syncthreads();  // h_s(t+1), enc_s(t+1) ready
  }

  for (int i = tid; i < 8 * 2048; i += 1024) {
    int bb = i >> 11, r = i & 2047, cc = r >> 4, p = r & 15;
    hout[((size_t)(b0 + bb) * 128 + cc) * 16 + p] =
        h_s[bb * HB_STRIDE + cc * HC_STRIDE + p];
  }
}

__global__ __launch_bounds__(128) void cls_kernel(
    const float* __restrict__ h, const float* __restrict__ w1,
    const float* __restrict__ b1, const float* __restrict__ w2,
    const float* __restrict__ b2, float* __restrict__ out) {
  __shared__ __align__(16) float feat[8 * 2048];
  __shared__ float hid[8 * 128];
  int b0 = blockIdx.x * 8;
  {
    const float4* src = (const float4*)(h + (size_t)b0 * 2048);
    float4* dst = (float4*)feat;
    for (int i = threadIdx.x; i < 4096; i += 128) dst[i] = src[i];
  }
  __syncthreads();
  int ch = threadIdx.x;
  float acc[8];
#pragma unroll
  for (int b = 0; b < 8; ++b) acc[b] = b1[ch];
  const float4* wr = (const float4*)(w1 + (size_t)ch * 2048);
  for (int k4 = 0; k4 < 512; ++k4) {
    float4 w = wr[k4];
#pragma unroll
    for (int b = 0; b < 8; ++b) {
      float4 f = ((const float4*)(feat + b * 2048))[k4];
      acc[b] += w.x * f.x + w.y * f.y + w.z * f.z + w.w * f.w;
    }
  }
#pragma unroll
  for (int b = 0; b < 8; ++b) hid[b * 128 + ch] = fmaxf(acc[b], 0.f);
  __syncthreads();
  if (threadIdx.x < 16) {
    int b = threadIdx.x >> 1, o = threadIdx.x & 1;
    float s = b2[o];
    for (int k = 0; k < 128; ++k) s += hid[b * 128 + k] * w2[o * 128 + k];
    out[(size_t)(b0 + b) * 2 + o] = s;
  }
}

extern "C" void kernel_launch(void* const* d_in, const int* in_sizes, int n_in,
                              void* d_out, int out_size, void* d_ws, size_t ws_size,
                              hipStream_t stream) {
  const float* x        = (const float*)d_in[0];
  const float* conv1d_w = (const float*)d_in[1];
  const float* conv1d_b = (const float*)d_in[2];
  const float* bn_gamma = (const float*)d_in[3];
  const float* bn_beta  = (const float*)d_in[4];
  const float* bn_mean  = (const float*)d_in[5];
  const float* bn_var   = (const float*)d_in[6];
  const float* lin_w    = (const float*)d_in[7];
  const float* lin_b    = (const float*)d_in[8];
  const float* cell_w   = (const float*)d_in[9];
  const float* cell_b   = (const float*)d_in[10];
  const float* cls1_w   = (const float*)d_in[11];
  const float* cls1_b   = (const float*)d_in[12];
  const float* cls2_w   = (const float*)d_in[13];
  const float* cls2_b   = (const float*)d_in[14];

  float* ws    = (float*)d_ws;
  float* We    = ws + 0;
  float* be    = ws + 8192;
  float* W2    = ws + 12288;
  float* A     = ws + 81920;
  float* Abias = ws + 344064;
  float* enc   = ws + 352256;
  _Float16* Apk = (_Float16*)(ws + 17129472);
  _Float16* Wpk = (_Float16*)(ws + 17260544);
  float* hbuf  = ws + 17391616;
  float* out   = (float*)d_out;

  prep_enc_w<<<21, 256, 0, stream>>>(conv1d_w, conv1d_b, bn_gamma, bn_beta,
                                     bn_mean, bn_var, We, be);
  prep_w2<<<256, 256, 0, stream>>>(lin_w, W2);
  prep_A<<<1024, 256, 0, stream>>>(cell_w, cell_b, lin_b, W2, A, Abias);
  pack_apk<<<1024, 256, 0, stream>>>(A, Apk);
  pack_wpk<<<1024, 256, 0, stream>>>(cell_w, Wpk);
  encoder_kernel<<<1024, 256, 0, stream>>>(x, We, be, enc);
  recur_kernel<<<256, 1024, 0, stream>>>(enc, Apk, Abias, Wpk, cell_b, hbuf);
  cls_kernel<<<256, 128, 0, stream>>>(hbuf, cls1_w, cls1_b, cls2_w, cls2_b, out);
}

// Round 3
// 14133.029 us; speedup vs baseline: 2.0133x; 1.6640x over previous
//
#include <hip/hip_runtime.h>
#include <math.h>

#define BN_EPS 1e-5f

typedef _Float16 f16x8 __attribute__((ext_vector_type(8)));
typedef _Float16 f16x4 __attribute__((ext_vector_type(4)));
typedef float f32x4 __attribute__((ext_vector_type(4)));
typedef float f32x16 __attribute__((ext_vector_type(16)));

// ---------------------------------------------------------------------------
// Workspace layout (float offsets):
//  We    @ 0        (5376)    encoder weight, BN folded
//  be    @ 8192     (64)
//  W2    @ 12288    (65536)   lin_w repeat-16 folded [o2][c] fp32
//  A     @ 81920    (262144)  x-path gates i,f: [go][c][p] fp32
//  Abias @ 344064   (4096)    bias for go 0..255 (incl cell_b, lin_b path)
//  Apk   @ 352256   (131072 fl = 262144 halves) MFMA A-frags [go][kch][lane][8]
//  Wcv   @ 483328   (73728 fl = 147456 halves)  conv A-frags [f|o|g][kch][tap][m][512]
//  enc16 @ 557056   (8388608 fl = 16.7M halves) [b*128+t][c] f16
//  hbuf  @ 8945664  (4194304) final h fp32 [b][ch][p]
// ---------------------------------------------------------------------------

__global__ void prep_enc_w(const float* __restrict__ conv1d_w,
                           const float* __restrict__ conv1d_b,
                           const float* __restrict__ gamma,
                           const float* __restrict__ beta,
                           const float* __restrict__ mean,
                           const float* __restrict__ var,
                           float* __restrict__ We, float* __restrict__ be) {
  int tid = blockIdx.x * blockDim.x + threadIdx.x;
  if (tid < 5376) {
    int c = tid / 84, f = tid % 84;
    float s = gamma[c] * rsqrtf(var[c] + BN_EPS);
    We[c * 84 + f] = s * conv1d_w[c * 252 + f * 3 + 1];
    if (f == 0) be[c] = s * conv1d_b[c] + (beta[c] - mean[c] * s);
  }
}

__global__ void prep_w2(const float* __restrict__ lin_w, float* __restrict__ W2) {
  int tid = blockIdx.x * blockDim.x + threadIdx.x;  // 65536
  int o2 = tid >> 6, c = tid & 63;
  float s = 0.f;
#pragma unroll
  for (int j = 0; j < 16; ++j) s += lin_w[o2 * 1024 + c * 16 + j];
  W2[o2 * 64 + c] = s;
}

__global__ void prep_A(const float* __restrict__ cell_w,
                       const float* __restrict__ cell_b,
                       const float* __restrict__ lin_b,
                       const float* __restrict__ W2,
                       float* __restrict__ A, float* __restrict__ Abias) {
  int tid = blockIdx.x * blockDim.x + threadIdx.x;  // 262144
  int go = tid >> 10;
  int c = (tid >> 4) & 63;
  int p = tid & 15;
  int y = p >> 2, x = p & 3;
  int kn = (go >= 128) ? 16 : 48;
  int xb = (go >= 128) ? 48 : 0;
  float a = 0.f;
  for (int k = 0; k < kn; ++k)
    for (int dy = 0; dy < 3; ++dy) {
      int yy = y + dy - 1;
      if (yy < 0 || yy > 3) continue;
      for (int dx = 0; dx < 3; ++dx) {
        int xx = x + dx - 1;
        if (xx < 0 || xx > 3) continue;
        a += cell_w[((go * 48 + k) * 3 + dy) * 3 + dx] *
             W2[((xb + k) * 16 + yy * 4 + xx) * 64 + c];
      }
    }
  A[(go * 64 + c) * 16 + p] = a;
  if (c == 0) {
    float bs = cell_b[go];
    for (int k = 0; k < kn; ++k)
      for (int dy = 0; dy < 3; ++dy) {
        int yy = y + dy - 1;
        if (yy < 0 || yy > 3) continue;
        for (int dx = 0; dx < 3; ++dx) {
          int xx = x + dx - 1;
          if (xx < 0 || xx > 3) continue;
          bs += cell_w[((go * 48 + k) * 3 + dy) * 3 + dx] *
                lin_b[(xb + k) * 16 + yy * 4 + xx];
        }
      }
    Abias[go * 16 + p] = bs;
  }
}

// A fp32 [go][c][p] -> MFMA 16x16x32 A-frags f16: Apk[go][kch][lane][8]
// lane: m=p=lane&15, k-group=(lane>>4); element j: c = kch*32 + (lane>>4)*8 + j
__global__ void pack_a16(const float* __restrict__ A, _Float16* __restrict__ Apk) {
  int tid = blockIdx.x * blockDim.x + threadIdx.x;  // 262144
  int j = tid & 7, lane = (tid >> 3) & 63, kch = (tid >> 9) & 1, go = tid >> 10;
  int p = lane & 15;
  int c = kch * 32 + (lane >> 4) * 8 + j;
  Apk[tid] = (_Float16)A[(go * 64 + c) * 16 + p];
}

// cell_w -> MFMA 32x32x16 conv A-frags f16:
// Wcv[f: kch0..1 | o: kch0..2 | g: kch0..2][tap][m][lane][8]
// lane: co = m*32 + (lane&31); element j: ci_local = kch*16 + (lane>>5)*8 + j
__global__ void pack_wcv(const float* __restrict__ cell_w, _Float16* __restrict__ Wcv) {
  int tid = blockIdx.x * blockDim.x + threadIdx.x;  // 147456
  int j = tid & 7, lane = (tid >> 3) & 63, m = (tid >> 9) & 3, tmk = tid >> 11;
  int co = m * 32 + (lane & 31);
  int khi = (lane >> 5) * 8 + j;
  float v;
  if (tmk < 18) {          // gate f: conv input = h 0..31 -> local k 16..47
    int kch = tmk / 9, tap = tmk % 9;
    int ci = kch * 16 + khi;           // 0..31
    v = cell_w[((size_t)(128 + co) * 48 + 16 + ci) * 9 + tap];
  } else if (tmk < 45) {   // gate o: h 32..79 -> local 0..47
    int r = tmk - 18; int kch = r / 9, tap = r % 9;
    int ci = kch * 16 + khi;
    v = cell_w[((size_t)(256 + co) * 48 + ci) * 9 + tap];
  } else {                 // gate g: h 80..127
    int r = tmk - 45; int kch = r / 9, tap = r % 9;
    int ci = kch * 16 + khi;
    v = cell_w[((size_t)(384 + co) * 48 + ci) * 9 + tap];
  }
  Wcv[tid] = (_Float16)v;
}

__global__ __launch_bounds__(256) void encoder_kernel(
    const float* __restrict__ x, const float* __restrict__ We,
    const float* __restrict__ be, _Float16* __restrict__ enc16) {
  int r = blockIdx.x * 256 + threadIdx.x;  // 262144 rows
  float4 xr[21];
  const float4* xp = (const float4*)(x + (size_t)r * 84);
#pragma unroll
  for (int i = 0; i < 21; ++i) xr[i] = xp[i];
  f16x4* ep = (f16x4*)(enc16 + (size_t)r * 64);
  for (int c4 = 0; c4 < 16; ++c4) {
    f16x4 o4;
#pragma unroll
    for (int cc = 0; cc < 4; ++cc) {
      int c = c4 * 4 + cc;
      float a = be[c];
      const float* wc = We + c * 84;
#pragma unroll
      for (int i = 0; i < 21; ++i) {
        a += xr[i].x * wc[i * 4 + 0] + xr[i].y * wc[i * 4 + 1] +
             xr[i].z * wc[i * 4 + 2] + xr[i].w * wc[i * 4 + 3];
      }
      o4[cc] = (_Float16)fmaxf(a, 0.f);
    }
    ep[c4] = o4;
  }
}

__device__ __forceinline__ float sigm(float v) {
  return __fdividef(1.f, 1.f + __expf(-v));
}
__device__ __forceinline__ float tanh_fast(float v) {
  return 1.f - __fdividef(2.f, __expf(2.f * v) + 1.f);
}

// LDS layout (bytes):
//  h_pad: [b][q 0..15][ci 0..127] f16, q-stride 272, b-stride 4368  (34944 B)
//  zero row @ 34944 (272 B of zeros)
//  G @ 35216: [ch][b][p] f32, ch-stride 528 B (132 dw), b-stride 64 B (67584 B)
#define HP_B 4368
#define HP_Q 272
#define ZOFF 34944
#define GOFF 35216
#define GB_CH 528
#define LDS_BYTES 102800

// Persistent MFMA recurrence: 256 blocks x 1024 threads (16 waves), 8 batches/block.
__global__ __launch_bounds__(1024) void recur_kernel(
    const _Float16* __restrict__ enc16, const _Float16* __restrict__ Apk,
    const float* __restrict__ Abias, const _Float16* __restrict__ Wcv,
    const float* __restrict__ cell_b, float* __restrict__ hout) {
  __shared__ __align__(16) unsigned char lds[LDS_BYTES];

  const int tid = threadIdx.x;
  const int lane = tid & 63;
  const int w = tid >> 6;
  const int b0 = blockIdx.x * 8;

  // zero h_pad + zero-row (G needs no init; fully written before read)
  for (int i = tid; i < (GOFF / 4); i += 1024) ((float*)lds)[i] = 0.f;

  // ---- consume-role constants: thread = (ch, b) ----
  const int ch = tid >> 3, b = tid & 7;
  const float cbo = cell_b[256 + ch], cbg = cell_b[384 + ch];
  const unsigned grd = GOFF + ch * GB_CH + b * 64;   // G read base
  const unsigned hwr = b * HP_B + ch * 2;            // h_pad write base

  // ---- A-part (16x16x32) constants ----
  const int bA = lane & 7;          // B n-index (lanes 8..15 duplicate)
  const int kgrp = lane >> 4;       // 0..3
  const bool adump_ok = (lane & 15) < 8;
  const unsigned adw = (unsigned)((lane & 15) * 64 + kgrp * 16);

  // ---- conv (32x32x16) constants: wave = (m, nt) ----
  const int m = w >> 2, nt = w & 3;
  const int col = lane & 31, khalf = lane >> 5;
  const int b_lo = col >> 4, p_c = col & 15;
  const int bcv = nt * 2 + b_lo;
  const int yc = p_c >> 2, xc = p_c & 3;
  unsigned baddr[9];
#pragma unroll
  for (int dy = 0; dy < 3; ++dy)
#pragma unroll
    for (int dx = 0; dx < 3; ++dx) {
      int qy = yc + dy - 1, qx = xc + dx - 1;
      bool valid = (qy >= 0 && qy < 4 && qx >= 0 && qx < 4);
      baddr[dy * 3 + dx] =
          (valid ? (unsigned)(bcv * HP_B + (qy * 4 + qx) * HP_Q) : (unsigned)ZOFF) +
          (unsigned)(khalf * 16);
    }
  const unsigned cdw = GOFF + bcv * 64 + p_c * 4;  // + (m*32+co_l)*528

  float c_r[16];
#pragma unroll
  for (int i = 0; i < 16; ++i) c_r[i] = 0.f;
  float si[16], tmpf[16];

  const _Float16* encb = enc16 + (size_t)(b0 + bA) * 128 * 64;
  const _Float16* WcvF = Wcv;                  // 2 kch
  const _Float16* WcvO = Wcv + 36864;          // 3 kch
  const _Float16* WcvG = Wcv + 92160;          // 3 kch

  __syncthreads();

  for (int t = 0; t < 128; ++t) {
    // B-frags for x-path (shared by gates i and f)
    f16x8 eb0 = *(const f16x8*)(encb + t * 64 + 0 + kgrp * 8);
    f16x8 eb1 = *(const f16x8*)(encb + t * 64 + 32 + kgrp * 8);

    // ---- phase 1: gate i x-part (go = w*8 + mt) ----
#pragma unroll
    for (int mt = 0; mt < 8; ++mt) {
      int go = w * 8 + mt;
      f32x4 acc = *(const f32x4*)(Abias + go * 16 + kgrp * 4);
      f16x8 a0 = *(const f16x8*)(Apk + ((size_t)go * 2 + 0) * 512 + lane * 8);
      f16x8 a1 = *(const f16x8*)(Apk + ((size_t)go * 2 + 1) * 512 + lane * 8);
      acc = __builtin_amdgcn_mfma_f32_16x16x32_f16(a0, eb0, acc, 0, 0, 0);
      acc = __builtin_amdgcn_mfma_f32_16x16x32_f16(a1, eb1, acc, 0, 0, 0);
      if (adump_ok) *(f32x4*)(lds + GOFF + go * GB_CH + adw) = acc;
    }
    __syncthreads();
    {  // consume: si = sigm(G)
      const float* g = (const float*)(lds + grd);
#pragma unroll
      for (int p = 0; p < 16; ++p) si[p] = sigm(g[p]);
    }
    __syncthreads();

    // ---- phase 2: gate f x-part (go = 128 + w*8 + mt) ----
#pragma unroll
    for (int mt = 0; mt < 8; ++mt) {
      int go = 128 + w * 8 + mt;
      f32x4 acc = *(const f32x4*)(Abias + go * 16 + kgrp * 4);
      f16x8 a0 = *(const f16x8*)(Apk + ((size_t)go * 2 + 0) * 512 + lane * 8);
      f16x8 a1 = *(const f16x8*)(Apk + ((size_t)go * 2 + 1) * 512 + lane * 8);
      acc = __builtin_amdgcn_mfma_f32_16x16x32_f16(a0, eb0, acc, 0, 0, 0);
      acc = __builtin_amdgcn_mfma_f32_16x16x32_f16(a1, eb1, acc, 0, 0, 0);
      if (adump_ok) *(f32x4*)(lds + GOFF + (go - 128) * GB_CH + adw) = acc;
    }
    __syncthreads();
    {  // stash x-part of f
      const float* g = (const float*)(lds + grd);
#pragma unroll
      for (int p = 0; p < 16; ++p) tmpf[p] = g[p];
    }
    __syncthreads();

    // ---- phase 3: gate f conv (h-ci 0..31, 2 kch) ----
    {
      f32x16 acc = {};
      const _Float16* wp = WcvF + (size_t)m * 512 + lane * 8;
#pragma unroll
      for (int kch = 0; kch < 2; ++kch)
#pragma unroll
        for (int tap = 0; tap < 9; ++tap) {
          f16x8 af = *(const f16x8*)(wp + (size_t)((kch * 9 + tap) * 4) * 512);
          f16x8 bf = *(const f16x8*)(lds + baddr[tap] + 0 + kch * 32);
          acc = __builtin_amdgcn_mfma_f32_32x32x16_f16(af, bf, acc, 0, 0, 0);
        }
#pragma unroll
      for (int r = 0; r < 16; ++r) {
        int co_l = (r & 3) + 8 * (r >> 2) + 4 * khalf;
        *(float*)(lds + cdw + (m * 32 + co_l) * GB_CH) = acc[r];
      }
    }
    __syncthreads();
    {  // consume: c *= sigm(f)
      const float* g = (const float*)(lds + grd);
#pragma unroll
      for (int p = 0; p < 16; ++p) c_r[p] *= sigm(tmpf[p] + g[p]);
    }
    __syncthreads();

    // ---- phase 4: gate g conv (h-ci 80..127, 3 kch) ----
    {
      f32x16 acc = {};
      const _Float16* wp = WcvG + (size_t)m * 512 + lane * 8;
#pragma unroll
      for (int kch = 0; kch < 3; ++kch)
#pragma unroll
        for (int tap = 0; tap < 9; ++tap) {
          f16x8 af = *(const f16x8*)(wp + (size_t)((kch * 9 + tap) * 4) * 512);
          f16x8 bf = *(const f16x8*)(lds + baddr[tap] + 160 + kch * 32);
          acc = __builtin_amdgcn_mfma_f32_32x32x16_f16(af, bf, acc, 0, 0, 0);
        }
#pragma unroll
      for (int r = 0; r < 16; ++r) {
        int co_l = (r & 3) + 8 * (r >> 2) + 4 * khalf;
        *(float*)(lds + cdw + (m * 32 + co_l) * GB_CH) = acc[r];
      }
    }
    __syncthreads();
    {  // consume: c += sigm(i) * tanh(g)
      const float* g = (const float*)(lds + grd);
#pragma unroll
      for (int p = 0; p < 16; ++p) c_r[p] += si[p] * tanh_fast(cbg + g[p]);
    }
    __syncthreads();

    // ---- phase 5: gate o conv (h-ci 32..79, 3 kch) ----
    {
      f32x16 acc = {};
      const _Float16* wp = WcvO + (size_t)m * 512 + lane * 8;
#pragma unroll
      for (int kch = 0; kch < 3; ++kch)
#pragma unroll
        for (int tap = 0; tap < 9; ++tap) {
          f16x8 af = *(const f16x8*)(wp + (size_t)((kch * 9 + tap) * 4) * 512);
          f16x8 bf = *(const f16x8*)(lds + baddr[tap] + 64 + kch * 32);
          acc = __builtin_amdgcn_mfma_f32_32x32x16_f16(af, bf, acc, 0, 0, 0);
        }
#pragma unroll
      for (int r = 0; r < 16; ++r) {
        int co_l = (r & 3) + 8 * (r >> 2) + 4 * khalf;
        *(float*)(lds + cdw + (m * 32 + co_l) * GB_CH) = acc[r];
      }
    }
    __syncthreads();
    {  // consume: h = sigm(o) * tanh(c); write h_pad (f16)
      const float* g = (const float*)(lds + grd);
      float hn[16];
#pragma unroll
      for (int p = 0; p < 16; ++p) hn[p] = sigm(cbo + g[p]) * tanh_fast(c_r[p]);
#pragma unroll
      for (int p = 0; p < 16; ++p)
        *(_Float16*)(lds + hwr + p * HP_Q) = (_Float16)hn[p];
      if (t == 127) {
        float* hp = hout + ((size_t)(b0 + b) * 128 + ch) * 16;
#pragma unroll
        for (int p = 0; p < 16; ++p) hp[p] = hn[p];
      }
    }
    __syncthreads();
  }
}

__global__ __launch_bounds__(128) void cls_kernel(
    const float* __restrict__ h, const float* __restrict__ w1,
    const float* __restrict__ b1, const float* __restrict__ w2,
    const float* __restrict__ b2, float* __restrict__ out) {
  __shared__ __align__(16) float feat[8 * 2048];
  __shared__ float hid[8 * 128];
  int b0 = blockIdx.x * 8;
  {
    const float4* src = (const float4*)(h + (size_t)b0 * 2048);
    float4* dst = (float4*)feat;
    for (int i = threadIdx.x; i < 4096; i += 128) dst[i] = src[i];
  }
  __syncthreads();
  int ch = threadIdx.x;
  float acc[8];
#pragma unroll
  for (int b = 0; b < 8; ++b) acc[b] = b1[ch];
  const float4* wr = (const float4*)(w1 + (size_t)ch * 2048);
  for (int k4 = 0; k4 < 512; ++k4) {
    float4 w = wr[k4];
#pragma unroll
    for (int b = 0; b < 8; ++b) {
      float4 f = ((const float4*)(feat + b * 2048))[k4];
      acc[b] += w.x * f.x + w.y * f.y + w.z * f.z + w.w * f.w;
    }
  }
#pragma unroll
  for (int b = 0; b < 8; ++b) hid[b * 128 + ch] = fmaxf(acc[b], 0.f);
  __syncthreads();
  if (threadIdx.x < 16) {
    int b = threadIdx.x >> 1, o = threadIdx.x & 1;
    float s = b2[o];
    for (int k = 0; k < 128; ++k) s += hid[b * 128 + k] * w2[o * 128 + k];
    out[(size_t)(b0 + b) * 2 + o] = s;
  }
}

extern "C" void kernel_launch(void* const* d_in, const int* in_sizes, int n_in,
                              void* d_out, int out_size, void* d_ws, size_t ws_size,
                              hipStream_t stream) {
  const float* x        = (const float*)d_in[0];
  const float* conv1d_w = (const float*)d_in[1];
  const float* conv1d_b = (const float*)d_in[2];
  const float* bn_gamma = (const float*)d_in[3];
  const float* bn_beta  = (const float*)d_in[4];
  const float* bn_mean  = (const float*)d_in[5];
  const float* bn_var   = (const float*)d_in[6];
  const float* lin_w    = (const float*)d_in[7];
  const float* lin_b    = (const float*)d_in[8];
  const float* cell_w   = (const float*)d_in[9];
  const float* cell_b   = (const float*)d_in[10];
  const float* cls1_w   = (const float*)d_in[11];
  const float* cls1_b   = (const float*)d_in[12];
  const float* cls2_w   = (const float*)d_in[13];
  const float* cls2_b   = (const float*)d_in[14];

  float* ws     = (float*)d_ws;
  float* We     = ws + 0;
  float* be     = ws + 8192;
  float* W2     = ws + 12288;
  float* A      = ws + 81920;
  float* Abias  = ws + 344064;
  _Float16* Apk = (_Float16*)(ws + 352256);
  _Float16* Wcv = (_Float16*)(ws + 483328);
  _Float16* enc16 = (_Float16*)(ws + 557056);
  float* hbuf   = ws + 8945664;
  float* out    = (float*)d_out;

  prep_enc_w<<<21, 256, 0, stream>>>(conv1d_w, conv1d_b, bn_gamma, bn_beta,
                                     bn_mean, bn_var, We, be);
  prep_w2<<<256, 256, 0, stream>>>(lin_w, W2);
  prep_A<<<1024, 256, 0, stream>>>(cell_w, cell_b, lin_b, W2, A, Abias);
  pack_a16<<<1024, 256, 0, stream>>>(A, Apk);
  pack_wcv<<<576, 256, 0, stream>>>(cell_w, Wcv);
  encoder_kernel<<<1024, 256, 0, stream>>>(x, We, be, enc16);
  recur_kernel<<<256, 1024, 0, stream>>>(enc16, Apk, Abias, Wcv, cell_b, hbuf);
  cls_kernel<<<256, 128, 0, stream>>>(hbuf, cls1_w, cls1_b, cls2_w, cls2_b, out);
}

// Round 4
// 5081.638 us; speedup vs baseline: 5.5993x; 2.7812x over previous
//
#include <hip/hip_runtime.h>
#include <math.h>

#define BN_EPS 1e-5f

typedef _Float16 f16x8 __attribute__((ext_vector_type(8)));
typedef _Float16 f16x2 __attribute__((ext_vector_type(2)));
typedef unsigned short u16x8 __attribute__((ext_vector_type(8)));
typedef float f32x4 __attribute__((ext_vector_type(4)));
typedef float f32x16 __attribute__((ext_vector_type(16)));

// ---------------------------------------------------------------------------
// Workspace (float offsets):
//  We     @ 0        (5376)    f32 encoder weight (BN folded)
//  be     @ 8192     (64)
//  W2     @ 12288    (65536)   lin_w repeat-16 folded
//  A      @ 81920    (262144)  x-path i,f matrix fp32 [go][c][p]
//  Abias  @ 344064   (4096)
//  WeF    @ 348160   (6144 halves = 3072 fl)  stage-1 A-frags
//  Apk    @ 352256   (262144 halves = 131072 fl) stage-2 A-frags
//  Wcv    @ 483328   (147456 halves = 73728 fl)  conv A-frags
//  h16    @ 557056   (4194304 halves = 2097152 fl) h state [b][q][ch] f16
//  cstate @ 2654208  (4194304 fl) c state, thread-slot-mapped
//  sixf   @ 6848512  (67108864 halves = 33554432 fl) per-chunk [b][trel][ch][slot][p]
//  end 40402944 fl = 161.6 MB
// ---------------------------------------------------------------------------

__global__ void prep_enc_w(const float* __restrict__ conv1d_w,
                           const float* __restrict__ conv1d_b,
                           const float* __restrict__ gamma,
                           const float* __restrict__ beta,
                           const float* __restrict__ mean,
                           const float* __restrict__ var,
                           float* __restrict__ We, float* __restrict__ be) {
  int tid = blockIdx.x * blockDim.x + threadIdx.x;
  if (tid < 5376) {
    int c = tid / 84, f = tid % 84;
    float s = gamma[c] * rsqrtf(var[c] + BN_EPS);
    We[c * 84 + f] = s * conv1d_w[c * 252 + f * 3 + 1];
    if (f == 0) be[c] = s * conv1d_b[c] + (beta[c] - mean[c] * s);
  }
}

// stage-1 A-frags for encoder MFMA: WeF[(ct*3+kch)*64+lane][8], K padded 84->96
__global__ void prep_wef(const float* __restrict__ We, _Float16* __restrict__ WeF) {
  int tid = blockIdx.x * blockDim.x + threadIdx.x;  // 6144
  if (tid >= 6144) return;
  int j = tid & 7, lane = (tid >> 3) & 63, kch = (tid >> 9) % 3, ct = tid / 1536;
  int c = ct * 16 + (lane & 15);
  int k = kch * 32 + (lane >> 4) * 8 + j;
  WeF[tid] = (k < 84) ? (_Float16)We[c * 84 + k] : (_Float16)0.f;
}

__global__ void prep_w2(const float* __restrict__ lin_w, float* __restrict__ W2) {
  int tid = blockIdx.x * blockDim.x + threadIdx.x;  // 65536
  int o2 = tid >> 6, c = tid & 63;
  float s = 0.f;
#pragma unroll
  for (int j = 0; j < 16; ++j) s += lin_w[o2 * 1024 + c * 16 + j];
  W2[o2 * 64 + c] = s;
}

__global__ void prep_A(const float* __restrict__ cell_w,
                       const float* __restrict__ cell_b,
                       const float* __restrict__ lin_b,
                       const float* __restrict__ W2,
                       float* __restrict__ A, float* __restrict__ Abias) {
  int tid = blockIdx.x * blockDim.x + threadIdx.x;  // 262144
  int go = tid >> 10;
  int c = (tid >> 4) & 63;
  int p = tid & 15;
  int y = p >> 2, x = p & 3;
  int kn = (go >= 128) ? 16 : 48;
  int xb = (go >= 128) ? 48 : 0;
  float a = 0.f;
  for (int k = 0; k < kn; ++k)
    for (int dy = 0; dy < 3; ++dy) {
      int yy = y + dy - 1;
      if (yy < 0 || yy > 3) continue;
      for (int dx = 0; dx < 3; ++dx) {
        int xx = x + dx - 1;
        if (xx < 0 || xx > 3) continue;
        a += cell_w[((go * 48 + k) * 3 + dy) * 3 + dx] *
             W2[((xb + k) * 16 + yy * 4 + xx) * 64 + c];
      }
    }
  A[(go * 64 + c) * 16 + p] = a;
  if (c == 0) {
    float bs = cell_b[go];
    for (int k = 0; k < kn; ++k)
      for (int dy = 0; dy < 3; ++dy) {
        int yy = y + dy - 1;
        if (yy < 0 || yy > 3) continue;
        for (int dx = 0; dx < 3; ++dx) {
          int xx = x + dx - 1;
          if (xx < 0 || xx > 3) continue;
          bs += cell_w[((go * 48 + k) * 3 + dy) * 3 + dx] *
                lin_b[(xb + k) * 16 + yy * 4 + xx];
        }
      }
    Abias[go * 16 + p] = bs;
  }
}

// A fp32 [go][c][p] -> 16x16x32 A-frags: Apk[go][kch][lane][8]
__global__ void pack_a16(const float* __restrict__ A, _Float16* __restrict__ Apk) {
  int tid = blockIdx.x * blockDim.x + threadIdx.x;  // 262144
  int j = tid & 7, lane = (tid >> 3) & 63, kch = (tid >> 9) & 1, go = tid >> 10;
  int p = lane & 15;
  int c = kch * 32 + (lane >> 4) * 8 + j;
  Apk[tid] = (_Float16)A[(go * 64 + c) * 16 + p];
}

// cell_w -> 32x32x16 conv A-frags: [f 2kch | o 3kch | g 3kch][(kch*9+tap)*4+m][lane][8]
__global__ void pack_wcv(const float* __restrict__ cell_w, _Float16* __restrict__ Wcv) {
  int tid = blockIdx.x * blockDim.x + threadIdx.x;  // 147456
  int j = tid & 7, lane = (tid >> 3) & 63, m = (tid >> 9) & 3, tmk = tid >> 11;
  int co = m * 32 + (lane & 31);
  int khi = (lane >> 5) * 8 + j;
  float v;
  if (tmk < 18) {
    int kch = tmk / 9, tap = tmk % 9;
    v = cell_w[((size_t)(128 + co) * 48 + 16 + kch * 16 + khi) * 9 + tap];
  } else if (tmk < 45) {
    int r = tmk - 18; int kch = r / 9, tap = r % 9;
    v = cell_w[((size_t)(256 + co) * 48 + kch * 16 + khi) * 9 + tap];
  } else {
    int r = tmk - 45; int kch = r / 9, tap = r % 9;
    v = cell_w[((size_t)(384 + co) * 48 + kch * 16 + khi) * 9 + tap];
  }
  Wcv[tid] = (_Float16)v;
}

__device__ __forceinline__ float sigm(float v) {
  return __fdividef(1.f, 1.f + __expf(-v));
}
__device__ __forceinline__ float tanh_fast(float v) {
  return 1.f - __fdividef(2.f, __expf(2.f * v) + 1.f);
}

// ---------------------------------------------------------------------------
// xgate: per chunk, compute si (u16 fixed) and xf (f16 preact) for 8 steps.
// grid 256: block = (go-quad gq = bid>>6) x (cc-group cq = bid&63, 256 cc).
// ---------------------------------------------------------------------------
__global__ __launch_bounds__(256) void xgate_kernel(
    const float* __restrict__ x, const _Float16* __restrict__ WeF,
    const float* __restrict__ be, const _Float16* __restrict__ Apk,
    const float* __restrict__ Abias, unsigned short* __restrict__ sixf, int tc) {
  __shared__ __align__(16) _Float16 x16[256 * 104];   // 53248 B
  __shared__ __align__(16) _Float16 enc_s[256 * 72];  // 36864 B
  int tid = threadIdx.x, lane = tid & 63, w = tid >> 6;
  int gq = blockIdx.x >> 6, cq = blockIdx.x & 63;
  int n = lane & 15, kgrp = lane >> 4;

  // stage x (f32 -> f16, K zero-padded to 96, row stride 104)
  const float* xb = x + ((size_t)cq * 32 * 128 + (size_t)tc * 8) * 84;
  for (int i = tid; i < 21504; i += 256) {
    int ccl = i / 84, kk = i - ccl * 84;
    int bloc = ccl >> 3, trel = ccl & 7;
    x16[ccl * 104 + kk] = (_Float16)xb[(size_t)bloc * 10752 + trel * 84 + kk];
  }
  for (int i = tid; i < 5120; i += 256) {
    int ccl = i / 20, kk = 84 + (i - ccl * 20);
    x16[ccl * 104 + kk] = (_Float16)0.f;
  }
  __syncthreads();

  // stage 1: encoder; wave w = ctile
  for (int ct4 = 0; ct4 < 16; ++ct4) {
    f32x4 acc = *(const f32x4*)(be + w * 16 + kgrp * 4);
#pragma unroll
    for (int kch = 0; kch < 3; ++kch)
      acc = __builtin_amdgcn_mfma_f32_16x16x32_f16(
          *(const f16x8*)(WeF + ((w * 3 + kch) * 64 + lane) * 8),
          *(const f16x8*)(&x16[(ct4 * 16 + n) * 104 + kch * 32 + kgrp * 8]),
          acc, 0, 0, 0);
#pragma unroll
    for (int r = 0; r < 4; ++r)
      enc_s[(ct4 * 16 + n) * 72 + w * 16 + kgrp * 4 + r] =
          (_Float16)fmaxf(acc[r], 0.f);
  }
  __syncthreads();

  // stage 2: x-gates; wave handles go-range gq*64 + w*16
  for (int ct4 = 0; ct4 < 16; ++ct4) {
    int ccl = ct4 * 16 + n;
    int b = cq * 32 + (ccl >> 3), trel = ccl & 7;
#pragma unroll 2
    for (int gol = 0; gol < 16; ++gol) {
      int go = gq * 64 + w * 16 + gol;
      f32x4 acc = *(const f32x4*)(Abias + go * 16 + kgrp * 4);
      acc = __builtin_amdgcn_mfma_f32_16x16x32_f16(
          *(const f16x8*)(Apk + (size_t)go * 1024 + lane * 8),
          *(const f16x8*)(&enc_s[ccl * 72 + kgrp * 8]), acc, 0, 0, 0);
      acc = __builtin_amdgcn_mfma_f32_16x16x32_f16(
          *(const f16x8*)(Apk + (size_t)go * 1024 + 512 + lane * 8),
          *(const f16x8*)(&enc_s[ccl * 72 + 32 + kgrp * 8]), acc, 0, 0, 0);
      int ch = go & 127, slot = go >> 7;
      unsigned short* dst =
          sixf + ((((size_t)b * 8 + trel) * 128 + ch) * 2 + slot) * 16 + kgrp * 4;
      if (slot == 0) {
#pragma unroll
        for (int rp = 0; rp < 2; ++rp) {
          unsigned lo = (unsigned)(sigm(acc[rp * 2]) * 65535.f + 0.5f);
          unsigned hi = (unsigned)(sigm(acc[rp * 2 + 1]) * 65535.f + 0.5f);
          *(unsigned*)(dst + rp * 2) = lo | (hi << 16);
        }
      } else {
#pragma unroll
        for (int rp = 0; rp < 2; ++rp) {
          f16x2 pv = {(_Float16)acc[rp * 2], (_Float16)acc[rp * 2 + 1]};
          *(f16x2*)(dst + rp * 2) = pv;
        }
      }
    }
  }
}

// ---------------------------------------------------------------------------
// recur8: 8 steps, 256 blocks x 768 thr (12 waves). Wave = (gate f/o/g, m).
// Conv weights in VGPRs. h in LDS f16 (q-dim padded w/ zero row), G f32 in LDS
// for 4-batch halves. c in VGPRs, chunk state via global.
// LDS: h_pad [8b][17q][128ch+pad] @0 (8*4624=36992), G @36992: 3*[128ch pad272][4b][16p]
// ---------------------------------------------------------------------------
#define HPB 4624
#define HPQ 272
#define ZQ 4352
#define GOFF 36992
#define GGATE 34816
#define LDSZ 141440

__device__ __forceinline__ void cell_update(
    unsigned char* lds, const unsigned short* __restrict__ sixf_b,
    _Float16* __restrict__ h16_b, float* c, int ch, int bl, int hf, int t,
    float cbo, float cbg, bool lastT) {
  int b = hf * 4 + bl;
  const unsigned short* sp = sixf_b + (((size_t)b * 8 + t) * 128 + ch) * 32;
  u16x8 s0 = *(const u16x8*)(sp);
  u16x8 s1 = *(const u16x8*)(sp + 8);
  f16x8 x0 = *(const f16x8*)(sp + 16);
  f16x8 x1 = *(const f16x8*)(sp + 24);
  const float* Gf = (const float*)(lds + GOFF + 0 * GGATE + ch * 272 + bl * 64);
  const float* Go = (const float*)(lds + GOFF + 1 * GGATE + ch * 272 + bl * 64);
  const float* Gg = (const float*)(lds + GOFF + 2 * GGATE + ch * 272 + bl * 64);
#pragma unroll
  for (int p = 0; p < 16; ++p) {
    float si = (float)(p < 8 ? s0[p] : s1[p & 7]) * (1.f / 65535.f);
    float xf = (float)(p < 8 ? x0[p] : x1[p & 7]);
    float cv = sigm(xf + Gf[p]) * c[p] + si * tanh_fast(cbg + Gg[p]);
    c[p] = cv;
    float hn = sigm(cbo + Go[p]) * tanh_fast(cv);
    *(_Float16*)(lds + b * HPB + p * HPQ + ch * 2) = (_Float16)hn;
    if (lastT) h16_b[((size_t)b * 16 + p) * 128 + ch] = (_Float16)hn;
  }
}

template <int GATE>
__device__ __forceinline__ void role_loop(
    unsigned char* lds, const _Float16* __restrict__ Wg,
    const unsigned short* __restrict__ sixf_b, float* __restrict__ cst_b,
    _Float16* __restrict__ h16_b, const float* __restrict__ cell_b,
    int m, int lane, int tid, const unsigned* tapbase, unsigned gbase) {
  constexpr int NKCH = (GATE == 0) ? 2 : 3;
  constexpr unsigned CIOFF = (GATE == 0) ? 0u : (GATE == 1 ? 64u : 160u);
  f16x8 wr[NKCH * 9];
#pragma unroll
  for (int fi = 0; fi < NKCH * 9; ++fi)
    wr[fi] = *(const f16x8*)(Wg + (size_t)(fi * 4 + m) * 512 + (lane << 3));

  int idx = (GATE == 2) ? (tid - 256) : tid;
  int ch = idx >> 2, bl = idx & 3;
  constexpr bool own0 = (GATE != 2), own1 = (GATE != 1);
  float cbo = cell_b[256 + ch], cbg = cell_b[384 + ch];
  float* cp0 = cst_b + (size_t)tid * 16;
  float* cp1 = cst_b + (size_t)(512 + ((GATE == 0) ? tid : tid - 256)) * 16;
  float c0[16], c1[16];
  if (own0) {
#pragma unroll
    for (int p = 0; p < 16; ++p) c0[p] = cp0[p];
  }
  if (own1) {
#pragma unroll
    for (int p = 0; p < 16; ++p) c1[p] = cp1[p];
  }

  for (int t = 0; t < 8; ++t) {
#pragma unroll
    for (int hf = 0; hf < 2; ++hf) {
#pragma unroll
      for (int nt = 0; nt < 2; ++nt) {
        unsigned bofs = (unsigned)(hf * 4 + nt * 2) * HPB;
        f32x16 acc = {};
#pragma unroll
        for (int kch = 0; kch < NKCH; ++kch)
#pragma unroll
          for (int tap = 0; tap < 9; ++tap)
            acc = __builtin_amdgcn_mfma_f32_32x32x16_f16(
                wr[kch * 9 + tap],
                *(const f16x8*)(lds + tapbase[tap] + bofs + CIOFF +
                                (unsigned)kch * 32),
                acc, 0, 0, 0);
#pragma unroll
        for (int r = 0; r < 16; ++r) {
          unsigned co_l = (unsigned)((r & 3) + 8 * (r >> 2));
          *(float*)(lds + gbase + GATE * GGATE + co_l * 272u +
                    (unsigned)nt * 128u) = acc[r];
        }
      }
      __syncthreads();
      if (hf == 0) {
        if (own0)
          cell_update(lds, sixf_b, h16_b, c0, ch, bl, 0, t, cbo, cbg, t == 7);
      } else {
        if (own1)
          cell_update(lds, sixf_b, h16_b, c1, ch, bl, 1, t, cbo, cbg, t == 7);
      }
      __syncthreads();
    }
  }
  if (own0) {
#pragma unroll
    for (int p = 0; p < 16; ++p) cp0[p] = c0[p];
  }
  if (own1) {
#pragma unroll
    for (int p = 0; p < 16; ++p) cp1[p] = c1[p];
  }
}

__global__ __launch_bounds__(768, 3) void recur8_kernel(
    const unsigned short* __restrict__ sixf, const _Float16* __restrict__ Wcv,
    const float* __restrict__ cell_b, _Float16* __restrict__ h16,
    float* __restrict__ cstate) {
  __shared__ __align__(16) unsigned char lds[LDSZ];
  int tid = threadIdx.x, lane = tid & 63, w = tid >> 6;
  int gate = w >> 2, m = w & 3;

  _Float16* h16_b = h16 + (size_t)blockIdx.x * 16384;
  for (int i = tid; i < 16384; i += 768) {
    int bl8 = i >> 11, q = (i >> 7) & 15, chh = i & 127;
    *(_Float16*)(lds + bl8 * HPB + q * HPQ + chh * 2) = h16_b[i];
  }
  for (int i = tid; i < 1024; i += 768) {
    int bl8 = i >> 7, chh = i & 127;
    *(_Float16*)(lds + bl8 * HPB + ZQ + chh * 2) = (_Float16)0.f;
  }

  int col = lane & 31, khalf = lane >> 5, b_lo = col >> 4, p_c = col & 15;
  int yc = p_c >> 2, xc = p_c & 3;
  unsigned tapbase[9];
#pragma unroll
  for (int dy = 0; dy < 3; ++dy)
#pragma unroll
    for (int dx = 0; dx < 3; ++dx) {
      int qy = yc + dy - 1, qx = xc + dx - 1;
      bool valid = (qy >= 0 && qy < 4 && qx >= 0 && qx < 4);
      tapbase[dy * 3 + dx] =
          (valid ? (unsigned)((qy * 4 + qx) * HPQ) : (unsigned)ZQ) +
          (unsigned)(b_lo * HPB + khalf * 16);
    }
  unsigned gbase = GOFF + (unsigned)m * 8704u + (unsigned)b_lo * 64u +
                   (unsigned)p_c * 4u + (unsigned)khalf * 1088u;
  __syncthreads();

  const unsigned short* sixf_b = sixf + (size_t)blockIdx.x * 262144;
  float* cst_b = cstate + (size_t)blockIdx.x * 16384;
  if (gate == 0)
    role_loop<0>(lds, Wcv, sixf_b, cst_b, h16_b, cell_b, m, lane, tid, tapbase, gbase);
  else if (gate == 1)
    role_loop<1>(lds, Wcv + 36864, sixf_b, cst_b, h16_b, cell_b, m, lane, tid, tapbase, gbase);
  else
    role_loop<2>(lds, Wcv + 92160, sixf_b, cst_b, h16_b, cell_b, m, lane, tid, tapbase, gbase);
}

__global__ __launch_bounds__(128) void cls_kernel(
    const _Float16* __restrict__ h16, const float* __restrict__ w1,
    const float* __restrict__ b1, const float* __restrict__ w2,
    const float* __restrict__ b2, float* __restrict__ out) {
  __shared__ __align__(16) float feat[8 * 2064];
  __shared__ float hid[8 * 128];
  int b0 = blockIdx.x * 8;
  for (int i = threadIdx.x; i < 16384; i += 128) {
    int bl = i >> 11, r = i & 2047, p = r >> 7, chh = r & 127;
    feat[bl * 2064 + chh * 16 + p] = (float)h16[(size_t)b0 * 2048 + i];
  }
  __syncthreads();
  int ch = threadIdx.x;
  float acc[8];
#pragma unroll
  for (int b = 0; b < 8; ++b) acc[b] = b1[ch];
  const float4* wr = (const float4*)(w1 + (size_t)ch * 2048);
  for (int k4 = 0; k4 < 512; ++k4) {
    float4 wv = wr[k4];
#pragma unroll
    for (int b = 0; b < 8; ++b) {
      float4 f = *(const float4*)(&feat[b * 2064 + k4 * 4]);
      acc[b] += wv.x * f.x + wv.y * f.y + wv.z * f.z + wv.w * f.w;
    }
  }
#pragma unroll
  for (int b = 0; b < 8; ++b) hid[b * 128 + ch] = fmaxf(acc[b], 0.f);
  __syncthreads();
  if (threadIdx.x < 16) {
    int b = threadIdx.x >> 1, o = threadIdx.x & 1;
    float s = b2[o];
    for (int k = 0; k < 128; ++k) s += hid[b * 128 + k] * w2[o * 128 + k];
    out[(size_t)(b0 + b) * 2 + o] = s;
  }
}

extern "C" void kernel_launch(void* const* d_in, const int* in_sizes, int n_in,
                              void* d_out, int out_size, void* d_ws, size_t ws_size,
                              hipStream_t stream) {
  const float* x        = (const float*)d_in[0];
  const float* conv1d_w = (const float*)d_in[1];
  const float* conv1d_b = (const float*)d_in[2];
  const float* bn_gamma = (const float*)d_in[3];
  const float* bn_beta  = (const float*)d_in[4];
  const float* bn_mean  = (const float*)d_in[5];
  const float* bn_var   = (const float*)d_in[6];
  const float* lin_w    = (const float*)d_in[7];
  const float* lin_b    = (const float*)d_in[8];
  const float* cell_w   = (const float*)d_in[9];
  const float* cell_b   = (const float*)d_in[10];
  const float* cls1_w   = (const float*)d_in[11];
  const float* cls1_b   = (const float*)d_in[12];
  const float* cls2_w   = (const float*)d_in[13];
  const float* cls2_b   = (const float*)d_in[14];

  float* ws = (float*)d_ws;
  float* We    = ws + 0;
  float* be    = ws + 8192;
  float* W2    = ws + 12288;
  float* A     = ws + 81920;
  float* Abias = ws + 344064;
  _Float16* WeF = (_Float16*)(ws + 348160);
  _Float16* Apk = (_Float16*)(ws + 352256);
  _Float16* Wcv = (_Float16*)(ws + 483328);
  _Float16* h16 = (_Float16*)(ws + 557056);
  float* cstate = ws + 2654208;
  unsigned short* sixf = (unsigned short*)(ws + 6848512);
  float* out = (float*)d_out;

  prep_enc_w<<<21, 256, 0, stream>>>(conv1d_w, conv1d_b, bn_gamma, bn_beta,
                                     bn_mean, bn_var, We, be);
  prep_wef<<<24, 256, 0, stream>>>(We, WeF);
  prep_w2<<<256, 256, 0, stream>>>(lin_w, W2);
  prep_A<<<1024, 256, 0, stream>>>(cell_w, cell_b, lin_b, W2, A, Abias);
  pack_a16<<<1024, 256, 0, stream>>>(A, Apk);
  pack_wcv<<<576, 256, 0, stream>>>(cell_w, Wcv);
  hipMemsetAsync(h16, 0, 8388608, stream);
  hipMemsetAsync(cstate, 0, 16777216, stream);
  for (int tc = 0; tc < 16; ++tc) {
    xgate_kernel<<<256, 256, 0, stream>>>(x, WeF, be, Apk, Abias, sixf, tc);
    recur8_kernel<<<256, 768, 0, stream>>>(sixf, Wcv, cell_b, h16, cstate);
  }
  cls_kernel<<<256, 128, 0, stream>>>(h16, cls1_w, cls1_b, cls2_w, cls2_b, out);
}